// Round 3
// baseline (605.702 us; speedup 1.0000x reference)
//
#include <hip/hip_runtime.h>

// Round-6: FUSED. Rounds 0-2 showed kernel B's ~176us residual is structural
// (ws round-trip), not tunable: B was rewritten twice (coalescing, IC
// residency) for only -31us total, while A already sits at its compulsory-miss
// floor (FETCH 287MB = 9 fine tables x 4MB x 8 XCDs). This version deletes ws
// and B entirely: two passes of 8 levels each, accumulated in registers
// (out row = 128B = 2 lines of 8 levels -> each pass writes COMPLETE 64B
// half-rows via an LDS transpose, nontemporal full-line stores).
// Phasing: grid = 2048 blocks x 256 thr x 2 pts = exactly resident capacity;
// all blocks walk the level loop together (no block replacement -> no table
// mixing, unlike the old all-16-level fallback whose 2x-oversubscribed grid
// thrashed all fine tables concurrently).

#define TSIZE (1u << 19)
#define HMASK (TSIZE - 1u)
#define P1 2654435761u
#define P2 805459861u

typedef float f32x4 __attribute__((ext_vector_type(4)));
typedef float f32x2 __attribute__((ext_vector_type(2)));

static constexpr float RES_K[16] = {16.f, 20.f, 25.f, 32.f, 40.f, 50.f, 64.f, 80.f,
                                    101.f, 128.f, 161.f, 203.f, 256.f, 322.f, 406.f, 512.f};

__device__ __forceinline__ void gather_lerp(const float2* __restrict__ tab,
                                            const float fx, const float fy, const float fz,
                                            float& ra, float& rb)
{
    const float bx = floorf(fx), by = floorf(fy), bz = floorf(fz);
    const float wx = fx - bx, wy = fy - by, wz = fz - bz;

    const unsigned ix0 = (unsigned)(int)bx;              // * prime 1
    const unsigned iy0 = (unsigned)(int)by * P1;
    const unsigned iz0 = (unsigned)(int)bz * P2;
    const unsigned ix1 = ix0 + 1u, iy1 = iy0 + P1, iz1 = iz0 + P2;

    const float2 v000 = tab[(ix0 ^ iy0 ^ iz0) & HMASK];
    const float2 v001 = tab[(ix0 ^ iy0 ^ iz1) & HMASK];
    const float2 v010 = tab[(ix0 ^ iy1 ^ iz0) & HMASK];
    const float2 v011 = tab[(ix0 ^ iy1 ^ iz1) & HMASK];
    const float2 v100 = tab[(ix1 ^ iy0 ^ iz0) & HMASK];
    const float2 v101 = tab[(ix1 ^ iy0 ^ iz1) & HMASK];
    const float2 v110 = tab[(ix1 ^ iy1 ^ iz0) & HMASK];
    const float2 v111 = tab[(ix1 ^ iy1 ^ iz1) & HMASK];

    const float c00a = v000.x + wx * (v100.x - v000.x);
    const float c00b = v000.y + wx * (v100.y - v000.y);
    const float c01a = v001.x + wx * (v101.x - v001.x);
    const float c01b = v001.y + wx * (v101.y - v001.y);
    const float c10a = v010.x + wx * (v110.x - v010.x);
    const float c10b = v010.y + wx * (v110.y - v010.y);
    const float c11a = v011.x + wx * (v111.x - v011.x);
    const float c11b = v011.y + wx * (v111.y - v011.y);

    const float c0a = c00a + wy * (c10a - c00a);
    const float c0b = c00b + wy * (c10b - c00b);
    const float c1a = c01a + wy * (c11a - c01a);
    const float c1b = c01b + wy * (c11b - c01b);

    ra = c0a + wz * (c1a - c0a);
    rb = c0b + wz * (c1b - c0b);
}

// One pass: levels LBASE..LBASE+7 for 512 points per block (2 per thread).
// LBASE is a template parameter so RES_K folds to immediates.
template<int LBASE>
__global__ __launch_bounds__(256) void fused_pass_kernel(
    const float* __restrict__ x,
    const float* __restrict__ tables,
    float* __restrict__ out,
    int npoints)
{
    // [256 pts][17 floats]: stride 17 -> conflict-free b32 writes (17t mod 32
    // bijective) and 2-way (free) b32 reads on the store phase.
    __shared__ float tile[256 * 17];

    const int t  = threadIdx.x;
    const int P0 = blockIdx.x * 512;
    constexpr int PASSF = (LBASE / 8) * 16;   // float offset of this pass's half-row

    if (P0 + 512 <= npoints) {
        const int pA = P0 + t;
        const int pB = P0 + 256 + t;

        const float ax = x[3 * pA + 0] + 1.0f;
        const float ay = x[3 * pA + 1] + 1.0f;
        const float az = x[3 * pA + 2] + 1.0f;
        const float bx = x[3 * pB + 0] + 1.0f;
        const float by = x[3 * pB + 1] + 1.0f;
        const float bz = x[3 * pB + 2] + 1.0f;

        float acc[32];   // [q*16 + 2*l + f], all indices compile-time

#pragma unroll
        for (int l = 0; l < 8; ++l) {
            const float halfr = 0.5f * RES_K[LBASE + l];
            const float2* __restrict__ tab =
                (const float2*)tables + (size_t)(LBASE + l) * TSIZE;
            gather_lerp(tab, ax * halfr, ay * halfr, az * halfr,
                        acc[2 * l], acc[2 * l + 1]);
            gather_lerp(tab, bx * halfr, by * halfr, bz * halfr,
                        acc[16 + 2 * l], acc[16 + 2 * l + 1]);
        }

        // ---- chunk A: points P0..P0+255 ----
#pragma unroll
        for (int i = 0; i < 16; ++i)
            tile[t * 17 + i] = acc[i];
        __syncthreads();
        {
            float* obase = out + (size_t)P0 * 32 + PASSF;
#pragma unroll
            for (int k = 0; k < 4; ++k) {
                const int s  = k * 256 + t;
                const int pt = s >> 2;
                const int c  = s & 3;
                f32x4 q = { tile[pt * 17 + 4 * c + 0], tile[pt * 17 + 4 * c + 1],
                            tile[pt * 17 + 4 * c + 2], tile[pt * 17 + 4 * c + 3] };
                // full 64B lines per wave-store (4 lanes/line), write-only ->
                // nontemporal keeps out stream from evicting tables in L2/IC
                __builtin_nontemporal_store(q, (f32x4*)(obase + (size_t)pt * 32 + 4 * c));
            }
        }
        __syncthreads();

        // ---- chunk B: points P0+256..P0+511 ----
#pragma unroll
        for (int i = 0; i < 16; ++i)
            tile[t * 17 + i] = acc[16 + i];
        __syncthreads();
        {
            float* obase = out + (size_t)(P0 + 256) * 32 + PASSF;
#pragma unroll
            for (int k = 0; k < 4; ++k) {
                const int s  = k * 256 + t;
                const int pt = s >> 2;
                const int c  = s & 3;
                f32x4 q = { tile[pt * 17 + 4 * c + 0], tile[pt * 17 + 4 * c + 1],
                            tile[pt * 17 + 4 * c + 2], tile[pt * 17 + 4 * c + 3] };
                __builtin_nontemporal_store(q, (f32x4*)(obase + (size_t)pt * 32 + 4 * c));
            }
        }
    } else {
        // tail path (never taken at npoints=1M=2048*512, kept for safety)
#pragma unroll
        for (int q = 0; q < 2; ++q) {
            const int p = P0 + q * 256 + t;
            if (p >= npoints) continue;
            const float px = x[3 * p + 0] + 1.0f;
            const float py = x[3 * p + 1] + 1.0f;
            const float pz = x[3 * p + 2] + 1.0f;
            float r[16];
#pragma unroll
            for (int l = 0; l < 8; ++l) {
                const float halfr = 0.5f * RES_K[LBASE + l];
                const float2* __restrict__ tab =
                    (const float2*)tables + (size_t)(LBASE + l) * TSIZE;
                gather_lerp(tab, px * halfr, py * halfr, pz * halfr,
                            r[2 * l], r[2 * l + 1]);
            }
            float* orow = out + (size_t)p * 32 + PASSF;
#pragma unroll
            for (int i = 0; i < 4; ++i) {
                f32x4 v = { r[4 * i + 0], r[4 * i + 1], r[4 * i + 2], r[4 * i + 3] };
                *(f32x4*)(orow + 4 * i) = v;
            }
        }
    }
}

extern "C" void kernel_launch(void* const* d_in, const int* in_sizes, int n_in,
                              void* d_out, int out_size, void* d_ws, size_t ws_size,
                              hipStream_t stream) {
    const float* x      = (const float*)d_in[0];
    const float* tables = (const float*)d_in[1];
    float* out          = (float*)d_out;

    const int npoints = in_sizes[0] / 3;                 // 1048576

    dim3 block(256);
    dim3 grid((npoints + 511) / 512);                    // 2048 = resident capacity

    hipLaunchKernelGGL(fused_pass_kernel<0>, grid, block, 0, stream,
                       x, tables, out, npoints);
    hipLaunchKernelGGL(fused_pass_kernel<8>, grid, block, 0, stream,
                       x, tables, out, npoints);
}